// Round 12
// baseline (1110.938 us; speedup 1.0000x reference)
//
#include <hip/hip_runtime.h>

#define HDIM 256
#define KSTEPS 30
#define RPB 16            // rows per block (256 blocks -> all CUs)
#define NTHR 512          // 8 waves

typedef _Float16 f16x8 __attribute__((ext_vector_type(8)));
typedef float f32x4 __attribute__((ext_vector_type(4)));

__device__ __forceinline__ f32x4 mfma16(f16x8 a, f16x8 b, f32x4 c) {
  return __builtin_amdgcn_mfma_f32_16x16x32_f16(a, b, c, 0, 0, 0);
}

// fast transcendentals via v_exp_f32 / v_rcp_f32 (~2 ULP; threshold 0.037)
__device__ __forceinline__ float fsigm(float x) {
  return __builtin_amdgcn_rcpf(1.0f + __expf(-x));
}
__device__ __forceinline__ float ftanh(float x) {
  float t = __expf(2.0f * x);                 // inf for big x -> rcp=0 -> 1
  return 1.0f - 2.0f * __builtin_amdgcn_rcpf(t + 1.0f);
}
__device__ __forceinline__ float softplusf(float x) {
  return fmaxf(x, 0.0f) + log1pf(__expf(-fabsf(x)));
}

// swizzled byte offset for a [16][256] fp16 LDS tile (row stride 512B)
__device__ __forceinline__ int swz(int r, int c) {
  return r * 512 + ((c * 2) ^ ((r & 7) << 4));
}

__device__ __forceinline__ void wrsplit(char* hi, char* lo, int off, float v) {
  _Float16 h = (_Float16)v;
  *(_Float16*)(hi + off) = h;
  *(_Float16*)(lo + off) = (_Float16)(v - (float)h);
}
__device__ __forceinline__ float rdpair(const char* hi, const char* lo, int off) {
  return (float)*(const _Float16*)(hi + off) + (float)*(const _Float16*)(lo + off);
}

// async global->LDS, 16B per lane; dest = ldsbase + lane*16 (linear)
__device__ __forceinline__ void glds16(const _Float16* src, char* lds) {
  __builtin_amdgcn_global_load_lds(
      (const __attribute__((address_space(1))) unsigned int*)src,
      (__attribute__((address_space(3))) unsigned int*)lds, 16, 0, 0);
}

// stage one K=32 tile (6 frags x 1KB: [ct0:R,Z,N, ct1:R,Z,N]) into a slab buffer
// wp is per-lane: packed wave base + lane*8
#define STAGE6(wp, t, dst) do {                              \
  const _Float16* _s = (wp) + (t)*3072;                      \
  glds16(_s,        (dst));                                  \
  glds16(_s + 512,  (dst) + 1024);                           \
  glds16(_s + 1024, (dst) + 2048);                           \
  glds16(_s + 1536, (dst) + 3072);                           \
  glds16(_s + 2048, (dst) + 4096);                           \
  glds16(_s + 2560, (dst) + 5120);                           \
} while (0)

#define WAITV(n) do { asm volatile("s_waitcnt vmcnt(" #n ")"); \
  __builtin_amdgcn_sched_barrier(0); } while (0)

// ---------------- prep: conversions + mfma16-order weight packing + teW ----------------
// Packed layout: p = ((w*8 + t)*6 + (ct*3 + g))*512 + lane*8 + j
//   lane = ks*16 + c (ks = K-subgroup 0-3, c = col 0-15)
//   src row = w*32 + ct*16 + c + g*256 ; src col = t*32 + ks*8 + j
// After glds16 (linear lane*16 dest), lane's mfma16 B-frag for (t, ct, g) is
// at slab + (ct*3+g)*1024 + lane*16 -> conflict-free 2-lanes/bank read.
__global__ __launch_bounds__(256) void prep_kernel(
    const float* __restrict__ W1, const float* __restrict__ W2,
    const float* __restrict__ Wih0, const float* __restrict__ Whh0,
    const float* __restrict__ Wih1, const float* __restrict__ Whh1,
    const float* __restrict__ hf,
    _Float16* __restrict__ Whh0p, _Float16* __restrict__ Wih1p,
    _Float16* __restrict__ Whh1p,
    _Float16* __restrict__ W1h, _Float16* __restrict__ W1l,
    _Float16* __restrict__ W2h, _Float16* __restrict__ W2l,
    _Float16* __restrict__ Wih0hh, _Float16* __restrict__ Wih0hl,
    _Float16* __restrict__ hfh, _Float16* __restrict__ hfl,
    float* __restrict__ teW, int B)
{
  int e = blockIdx.x * 256 + threadIdx.x;
  if (e < 3*196608) {
    int m = e / 196608, p = e % 196608;
    int j = p & 7;
    int lane = (p >> 3) & 63;
    int c = lane & 15, ks = lane >> 4;
    int fi = (p >> 9) % 6;
    int wt = p / 3072;
    int t = wt & 7, wv = wt >> 3;
    int ct = fi / 3, g = fi % 3;
    int row = wv*32 + ct*16 + c + g*256;
    int col = t*32 + ks*8 + j;
    const float* src = (m == 0) ? Whh0 : (m == 1) ? Wih1 : Whh1;
    _Float16* dst = (m == 0) ? Whh0p : (m == 1) ? Wih1p : Whh1p;
    dst[p] = (_Float16)src[row*256 + col];
    return;
  } e -= 3*196608;
  if (e < 65536)  { float x = W1[e]; _Float16 h = (_Float16)x; W1h[e] = h; W1l[e] = (_Float16)(x - (float)h); return; } e -= 65536;
  if (e < 131072) { float x = W2[e]; _Float16 h = (_Float16)x; W2h[e] = h; W2l[e] = (_Float16)(x - (float)h); return; } e -= 131072;
  if (e < 196608) { int n = e >> 8, c = e & 255; float x = Wih0[n*291 + 35 + c]; _Float16 h = (_Float16)x; Wih0hh[e] = h; Wih0hl[e] = (_Float16)(x - (float)h); return; } e -= 196608;
  if (e < B*HDIM) { float x = hf[e]; _Float16 h = (_Float16)x; hfh[e] = h; hfl[e] = (_Float16)(x - (float)h); return; } e -= B*HDIM;
  if (e < KSTEPS*768) {
    int k = e / 768, n = e % 768;
    float pos = (float)k;
    const float fac = -9.210340371976184f / 31.0f;   // -ln(10000)/(TD-1)
    float acc = 0.0f;
    #pragma unroll
    for (int j = 0; j < 31; ++j) {
      int i = j >> 1;
      float ang = pos * expf((float)(2*i) * fac);
      float t = (j & 1) ? cosf(ang) : sinf(ang);
      acc += t * Wih0[n*291 + 3 + j];
    }
    acc += (pos / 30.0f) * Wih0[n*291 + 3 + 31];
    teW[e] = acc;
  }
}

// ------- XcT[n*B + r] = (hf @ Wih0[:,35:291].T)[r,n] + bih0[n]  (transposed, f32) -------
__global__ __launch_bounds__(64) void xc_kernel(
    const _Float16* __restrict__ hfh, const _Float16* __restrict__ hfl,
    const _Float16* __restrict__ Wh, const _Float16* __restrict__ Wl,
    const float* __restrict__ bih0, float* __restrict__ XcT, int B)
{
  int l = threadIdx.x, l15 = l & 15, l4 = l >> 4;
  int bm = blockIdx.x;
  int bn = blockIdx.y;
  f32x4 acc[4];
  #pragma unroll
  for (int i = 0; i < 4; ++i) acc[i] = (f32x4){0,0,0,0};
  const _Float16* ah = hfh + (size_t)(bm*16 + l15)*256 + l4*8;
  const _Float16* al = hfl + (size_t)(bm*16 + l15)*256 + l4*8;
  #pragma unroll
  for (int kk = 0; kk < 8; ++kk) {
    f16x8 aH = *(const f16x8*)(ah + kk*32);
    f16x8 aL = *(const f16x8*)(al + kk*32);
    #pragma unroll
    for (int i = 0; i < 4; ++i) {
      size_t boff = (size_t)(bn*64 + i*16 + l15)*256 + l4*8 + kk*32;
      f16x8 bH = *(const f16x8*)(Wh + boff);
      f16x8 bL = *(const f16x8*)(Wl + boff);
      acc[i] = mfma16(aH, bH, acc[i]);
      acc[i] = mfma16(aL, bH, acc[i]);
      acc[i] = mfma16(aH, bL, acc[i]);
    }
  }
  #pragma unroll
  for (int i = 0; i < 4; ++i) {
    int n = bn*64 + i*16 + l15;
    float bb = bih0[n];
    #pragma unroll
    for (int j = 0; j < 4; ++j) {
      int r = bm*16 + l4*4 + j;
      XcT[(size_t)n*B + r] = acc[i][j] + bb;
    }
  }
}

// ---------------- main persistent GRU kernel ----------------
// LDS map (bytes); h tiles [16][256] fp16 swizzled, 8KB each
#define OFF_H0H   0
#define OFF_H0L   8192
#define OFF_H1H   16384
#define OFF_H1L   24576
#define OFF_SLAB  32768    // 2 bufs x 48KB (8 waves x 6KB); also hmid temp in h_init
#define OFF_WS3   131072   // 768*3 f32
#define OFF_BHH0  140288
#define OFF_BI1   143360
#define OFF_BH1   146432
#define OFF_WOUT  149504
#define OFF_SPH   152576   // 16*8 f32
#define OFF_BOUT  153088
#define LDS_BYTES 153104   // <= 163840

__global__ __launch_bounds__(NTHR) void gru_main(
    const float* __restrict__ istate,
    const float* __restrict__ b1g, const float* __restrict__ b2g,
    const float* __restrict__ Wih0, const float* __restrict__ bhh0g,
    const float* __restrict__ bih1g, const float* __restrict__ bhh1g,
    const float* __restrict__ Woutg, const float* __restrict__ boutg,
    const _Float16* __restrict__ Whh0p, const _Float16* __restrict__ Wih1p,
    const _Float16* __restrict__ Whh1p,
    const _Float16* __restrict__ W1h, const _Float16* __restrict__ W1l,
    const _Float16* __restrict__ W2h, const _Float16* __restrict__ W2l,
    const _Float16* __restrict__ hfh, const _Float16* __restrict__ hfl,
    const float* __restrict__ teW, const float* __restrict__ XcT,
    float* __restrict__ out, int B)
{
  extern __shared__ char smem[];
  char* h0H = smem + OFF_H0H;  char* h0L = smem + OFF_H0L;
  char* h1H = smem + OFF_H1H;  char* h1L = smem + OFF_H1L;
  float* Ws3   = (float*)(smem + OFF_WS3);
  float* bhh0L = (float*)(smem + OFF_BHH0);
  float* bi1L  = (float*)(smem + OFF_BI1);
  float* bh1L  = (float*)(smem + OFF_BH1);
  float* WoutL = (float*)(smem + OFF_WOUT);
  float* sph   = (float*)(smem + OFF_SPH);
  float* boutL = (float*)(smem + OFF_BOUT);

  const int tid = threadIdx.x;
  const int w = tid >> 6;
  const int lane = tid & 63;
  const int l15 = lane & 15;
  const int l4 = lane >> 4;
  const int row0 = blockIdx.x * RPB;

  // wave-uniform slab bases (per-wave private 6KB region in each of 2 buffers)
  const int wsb = __builtin_amdgcn_readfirstlane(OFF_SLAB + w * 6144);
  char* sl0 = smem + wsb;
  char* sl1 = sl0 + 49152;

  // per-lane packed-weight bases (tile stride 3072 elems)
  const _Float16* wpB  = Whh0p + (size_t)w*24576 + lane*8;
  const _Float16* wpH1 = Whh1p + (size_t)w*24576 + lane*8;
  const _Float16* wpI1 = Wih1p + (size_t)w*24576 + lane*8;

  // ---- constants to LDS
  for (int i = tid; i < 2304; i += NTHR) Ws3[i] = Wih0[(i/3)*291 + (i%3)];
  for (int i = tid; i < 768; i += NTHR) {
    bhh0L[i] = bhh0g[i]; bi1L[i] = bih1g[i]; bh1L[i] = bhh1g[i]; WoutL[i] = Woutg[i];
  }
  if (tid < 3) boutL[tid] = boutg[tid];
  if (tid < RPB) {
    const float* is = istate + (size_t)(row0 + tid) * 3;
    float s0 = is[0], s1 = is[1], s2 = is[2];
    float* sp = sph + tid*8;
    sp[0] = s0; sp[1] = s1; sp[2] = s2;
    sp[3] = s0; sp[4] = s0; sp[5] = s0;
  }

  // ---- h_init GEMM1: relu(hf @ W1.T + b1), 16 rows -> hmid (hi/lo) in slab region
  {
    char* mH = smem + OFF_SLAB;
    char* mL = smem + OFF_SLAB + 8192;
    #pragma unroll
    for (int i = 0; i < 2; ++i) {
      int nt = w*2 + i;
      f32x4 acc0 = {0,0,0,0};
      const _Float16* brh = W1h + (nt*16 + l15)*256 + l4*8;
      const _Float16* brl = W1l + (nt*16 + l15)*256 + l4*8;
      const _Float16* a0h = hfh + (size_t)(row0 + l15)*256 + l4*8;
      const _Float16* a0l = hfl + (size_t)(row0 + l15)*256 + l4*8;
      #pragma unroll
      for (int kk = 0; kk < 8; ++kk) {
        f16x8 bH = *(const f16x8*)(brh + kk*32);
        f16x8 bL = *(const f16x8*)(brl + kk*32);
        f16x8 aH0 = *(const f16x8*)(a0h + kk*32);
        f16x8 aL0 = *(const f16x8*)(a0l + kk*32);
        acc0 = mfma16(aH0, bH, acc0); acc0 = mfma16(aL0, bH, acc0); acc0 = mfma16(aH0, bL, acc0);
      }
      int n = nt*16 + l15;
      float bb = b1g[n];
      #pragma unroll
      for (int j = 0; j < 4; ++j) {
        int r = l4*4 + j;
        float v = fmaxf(acc0[j] + bb, 0.0f);
        wrsplit(mH, mL, swz(r, n), v);
      }
    }
  }
  __syncthreads();

  // ---- h_init GEMM2: tanh(hmid @ W2.T + b2) -> h0 / h1 (hi/lo), 16 rows
  {
    const char* mH = smem + OFF_SLAB;
    const char* mL = smem + OFF_SLAB + 8192;
    #pragma unroll
    for (int i = 0; i < 4; ++i) {
      int nt = w*4 + i;
      f32x4 acc0 = {0,0,0,0};
      const _Float16* brh = W2h + (nt*16 + l15)*256 + l4*8;
      const _Float16* brl = W2l + (nt*16 + l15)*256 + l4*8;
      #pragma unroll
      for (int kk = 0; kk < 8; ++kk) {
        int kc = kk*32 + l4*8;
        f16x8 bH = *(const f16x8*)(brh + kk*32);
        f16x8 bL = *(const f16x8*)(brl + kk*32);
        f16x8 aH0 = *(const f16x8*)(mH + swz(l15, kc));
        f16x8 aL0 = *(const f16x8*)(mL + swz(l15, kc));
        acc0 = mfma16(aH0, bH, acc0); acc0 = mfma16(aL0, bH, acc0); acc0 = mfma16(aH0, bL, acc0);
      }
      int n = nt*16 + l15;
      float bb = b2g[n];
      #pragma unroll
      for (int j = 0; j < 4; ++j) {
        int r = l4*4 + j;
        float v = ftanh(acc0[j] + bb);
        if (n < 256) wrsplit(h0H, h0L, swz(r, n), v);
        else         wrsplit(h1H, h1L, swz(r, n - 256), v);
      }
    }
  }
  __syncthreads();

  const size_t outP = (size_t)B * KSTEPS;
  const int boff = lane * 16;          // packed slab B-frag offset: conflict-free
  const int n0 = w*32 + l15;           // ct=0 output col (per gate)
  const int n1 = n0 + 16;              // ct=1 output col

  // prologue: stage step-0 B tile 0
  STAGE6(wpB, 0, sl0);

  for (int k = 0; k < KSTEPS; ++k) {
    const float* teWk = teW + k*768;

    // ================= Phase B: gh0 = h0 @ Whh0.T (2-buf, dist-1) ===========
    f32x4 cR0 = {0,0,0,0}, cZ0 = {0,0,0,0}, cN0 = {0,0,0,0};
    f32x4 cR1 = {0,0,0,0}, cZ1 = {0,0,0,0}, cN1 = {0,0,0,0};
    #define GBODY(buf, t, AH, AL, r0, z0, nn0, r1, z1, nn1) do {      \
      f16x8 b0 = *(const f16x8*)((buf) + boff);                       \
      f16x8 b1 = *(const f16x8*)((buf) + 1024 + boff);                \
      f16x8 b2 = *(const f16x8*)((buf) + 2048 + boff);                \
      f16x8 b3 = *(const f16x8*)((buf) + 3072 + boff);                \
      f16x8 b4 = *(const f16x8*)((buf) + 4096 + boff);                \
      f16x8 b5 = *(const f16x8*)((buf) + 5120 + boff);                \
      int aoff = swz(l15, (t)*32 + l4*8);                             \
      f16x8 aH = *(const f16x8*)((AH) + aoff);                        \
      f16x8 aL = *(const f16x8*)((AL) + aoff);                        \
      r0  = mfma16(aH, b0, r0);  r0  = mfma16(aL, b0, r0);            \
      z0  = mfma16(aH, b1, z0);  z0  = mfma16(aL, b1, z0);            \
      nn0 = mfma16(aH, b2, nn0); nn0 = mfma16(aL, b2, nn0);           \
      r1  = mfma16(aH, b3, r1);  r1  = mfma16(aL, b3, r1);            \
      z1  = mfma16(aH, b4, z1);  z1  = mfma16(aL, b4, z1);            \
      nn1 = mfma16(aH, b5, nn1); nn1 = mfma16(aL, b5, nn1);           \
    } while (0)
    #pragma unroll
    for (int t = 0; t < 8; ++t) {
      char* cur = (t & 1) ? sl1 : sl0;
      char* nxt = (t & 1) ? sl0 : sl1;
      if (t < 7) STAGE6(wpB, t + 1, nxt);
      else       STAGE6(wpH1, 0, nxt);
      WAITV(6);
      GBODY(cur, t, h0H, h0L, cR0, cZ0, cN0, cR1, cZ1, cN1);
    }
    __syncthreads();   // all waves done reading h0_old

    // ---- GRU-0 epilogue, in-place h0 update (XcT loaded here, post-K-loop:
    //      keeping it out of the K-loop live range is what avoids spill)
    #define EPI0(n, accR, accZ, accN) do {                                      \
      size_t base = (size_t)row0 + l4*4;                                        \
      f32x4 xcR = *(const f32x4*)(XcT + (size_t)(n)*B + base);                  \
      f32x4 xcZ = *(const f32x4*)(XcT + (size_t)(256 + (n))*B + base);          \
      f32x4 xcN = *(const f32x4*)(XcT + (size_t)(512 + (n))*B + base);          \
      float teR = teWk[n], teZ = teWk[256 + (n)], teN = teWk[512 + (n)];        \
      float wR0 = Ws3[(n)*3+0],       wR1 = Ws3[(n)*3+1],       wR2 = Ws3[(n)*3+2];          \
      float wZ0 = Ws3[((n)+256)*3+0], wZ1 = Ws3[((n)+256)*3+1], wZ2 = Ws3[((n)+256)*3+2];    \
      float wN0 = Ws3[((n)+512)*3+0], wN1 = Ws3[((n)+512)*3+1], wN2 = Ws3[((n)+512)*3+2];    \
      float bhR = bhh0L[n], bhZ = bhh0L[256 + (n)], bhN = bhh0L[512 + (n)];     \
      _Pragma("unroll")                                                         \
      for (int j = 0; j < 4; ++j) {                                             \
        int r = l4*4 + j;                                                       \
        const float* sp = sph + r*8;                                            \
        float s0 = sp[0], s1 = sp[1], s2 = sp[2];                               \
        float giR = xcR[j] + teR + s0*wR0 + s1*wR1 + s2*wR2;                    \
        float giZ = xcZ[j] + teZ + s0*wZ0 + s1*wZ1 + s2*wZ2;                    \
        float giN = xcN[j] + teN + s0*wN0 + s1*wN1 + s2*wN2;                    \
        float rg = fsigm(giR + accR[j] + bhR);                                  \
        float zg = fsigm(giZ + accZ[j] + bhZ);                                  \
        float ng = ftanh(giN + rg * (accN[j] + bhN));                           \
        float hold = rdpair(h0H, h0L, swz(r, n));                               \
        float hnew = (1.0f - zg) * ng + zg * hold;                              \
        wrsplit(h0H, h0L, swz(r, n), hnew);                                     \
      }                                                                         \
    } while (0)
    EPI0(n0, cR0, cZ0, cN0);
    EPI0(n1, cR1, cZ1, cN1);
    #undef EPI0
    __syncthreads();   // h0_new visible to all

    // ===== Phase AC: K=512 concat GEMM [h1_old; h0_new] @ [Whh1; Wih1].T ====
    f32x4 aR0 = {0,0,0,0}, aZ0 = {0,0,0,0}, hN0 = {0,0,0,0}, iN0 = {0,0,0,0};
    f32x4 aR1 = {0,0,0,0}, aZ1 = {0,0,0,0}, hN1 = {0,0,0,0}, iN1 = {0,0,0,0};
    #pragma unroll
    for (int t = 0; t < 8; ++t) {     // sub0: h1_old x Whh1
      char* cur = (t & 1) ? sl1 : sl0;
      char* nxt = (t & 1) ? sl0 : sl1;
      if (t < 7) STAGE6(wpH1, t + 1, nxt);
      else       STAGE6(wpI1, 0, nxt);
      WAITV(6);
      GBODY(cur, t, h1H, h1L, aR0, aZ0, hN0, aR1, aZ1, hN1);
    }
    #pragma unroll
    for (int t = 0; t < 8; ++t) {     // sub1: h0_new x Wih1
      char* cur = (t & 1) ? sl1 : sl0;
      char* nxt = (t & 1) ? sl0 : sl1;
      if (t < 7) STAGE6(wpI1, t + 1, nxt);
      else       STAGE6(wpB, 0, nxt);   // prefetch next step's B tile 0
      WAITV(6);
      GBODY(cur, t, h0H, h0L, aR0, aZ0, iN0, aR1, aZ1, iN1);
    }
    #undef GBODY
    __syncthreads();   // all waves done reading h1_old

    // ---- GRU-1 epilogue, in-place h1 update
    #define EPI1(n, accR, accZ, accHN, accIN) do {                              \
      float biR = bi1L[n], biZ = bi1L[256+(n)], biN = bi1L[512+(n)];            \
      float bhRb = bh1L[n], bhZb = bh1L[256+(n)], bhNb = bh1L[512+(n)];         \
      _Pragma("unroll")                                                         \
      for (int j = 0; j < 4; ++j) {                                             \
        int r = l4*4 + j;                                                       \
        float rg = fsigm(accR[j] + biR + bhRb);                                 \
        float zg = fsigm(accZ[j] + biZ + bhZb);                                 \
        float ng = ftanh(accIN[j] + biN + rg * (accHN[j] + bhNb));              \
        float hold = rdpair(h1H, h1L, swz(r, n));                               \
        float hnew = (1.0f - zg) * ng + zg * hold;                              \
        wrsplit(h1H, h1L, swz(r, n), hnew);                                     \
      }                                                                         \
    } while (0)
    EPI1(n0, aR0, aZ0, hN0, iN0);
    EPI1(n1, aR1, aZ1, hN1, iN1);
    #undef EPI1
    __syncthreads();   // h1_new visible

    // ---- Phase D: qr = h1n @ Wout.T + bout (16 rows x 32 lanes)
    {
      int r = tid >> 5, li = tid & 31;
      float q0 = 0.0f, q1 = 0.0f, q2 = 0.0f;
      #pragma unroll
      for (int i = 0; i < 8; ++i) {
        int h = li + i*32;
        float v = rdpair(h1H, h1L, swz(r, h));
        q0 += v * WoutL[h];
        q1 += v * WoutL[256 + h];
        q2 += v * WoutL[512 + h];
      }
      #pragma unroll
      for (int m = 1; m < 32; m <<= 1) {
        q0 += __shfl_xor(q0, m);
        q1 += __shfl_xor(q1, m);
        q2 += __shfl_xor(q2, m);
      }
      if (li == 0) {
        float qlo = q0 + boutL[0];
        float qm  = qlo + softplusf(q1 + boutL[1] - qlo);
        float qhi = qm  + softplusf(q2 + boutL[2] - qm);
        size_t b = row0 + r;
        out[b*KSTEPS + k]            = qlo;
        out[outP + b*KSTEPS + k]     = qm;
        out[2*outP + b*KSTEPS + k]   = qhi;
        float* sp = sph + r*8;
        float p1 = sp[4], p2 = sp[5];
        sp[0] = qm;
        sp[1] = (qm - p1) * 5.0f;
        sp[2] = (qm - 2.0f*p2 + p1) * 100.0f;
        sp[3] = p1; sp[4] = p2; sp[5] = qm;
      }
    }
    // no barrier: next B K-loop reads only h0 + weight slabs (not h1/sph);
    // the first sph/h1 consumers are >=1 barrier away
  }
}

extern "C" void kernel_launch(void* const* d_in, const int* in_sizes, int n_in,
                              void* d_out, int out_size, void* d_ws, size_t ws_size,
                              hipStream_t stream) {
  const float* hf     = (const float*)d_in[0];
  const float* istate = (const float*)d_in[1];
  const float* W1     = (const float*)d_in[2];
  const float* b1     = (const float*)d_in[3];
  const float* W2     = (const float*)d_in[4];
  const float* b2     = (const float*)d_in[5];
  const float* Wih0   = (const float*)d_in[6];
  const float* Whh0   = (const float*)d_in[7];
  const float* bih0   = (const float*)d_in[8];
  const float* bhh0   = (const float*)d_in[9];
  const float* Wih1   = (const float*)d_in[10];
  const float* Whh1   = (const float*)d_in[11];
  const float* bih1   = (const float*)d_in[12];
  const float* bhh1   = (const float*)d_in[13];
  const float* Wout   = (const float*)d_in[14];
  const float* bout   = (const float*)d_in[15];
  float* out = (float*)d_out;
  const int B = in_sizes[0] / HDIM;   // 4096

  char* ws = (char*)d_ws;
  size_t o = 0;
  _Float16* Whh0p  = (_Float16*)(ws + o); o += 393216;
  _Float16* Wih1p  = (_Float16*)(ws + o); o += 393216;
  _Float16* Whh1p  = (_Float16*)(ws + o); o += 393216;
  _Float16* W1h    = (_Float16*)(ws + o); o += 131072;
  _Float16* W1l    = (_Float16*)(ws + o); o += 131072;
  _Float16* W2h    = (_Float16*)(ws + o); o += 262144;
  _Float16* W2l    = (_Float16*)(ws + o); o += 262144;
  _Float16* Wih0hh = (_Float16*)(ws + o); o += 393216;
  _Float16* Wih0hl = (_Float16*)(ws + o); o += 393216;
  _Float16* hfh    = (_Float16*)(ws + o); o += (size_t)B * HDIM * 2;
  _Float16* hfl    = (_Float16*)(ws + o); o += (size_t)B * HDIM * 2;
  float*    teW    = (float*)(ws + o);    o += (size_t)KSTEPS * 768 * 4;
  float*    XcT    = (float*)(ws + o);    o += (size_t)B * 768 * 4;
  if (ws_size < o) return;

  const int prep_total = 196608*3 + 65536 + 131072 + 196608 + B*HDIM + KSTEPS*768;
  prep_kernel<<<dim3((prep_total + 255) / 256), dim3(256), 0, stream>>>(
      W1, W2, Wih0, Whh0, Wih1, Whh1, hf,
      Whh0p, Wih1p, Whh1p, W1h, W1l, W2h, W2l, Wih0hh, Wih0hl, hfh, hfl, teW, B);

  xc_kernel<<<dim3(B/16, 12), dim3(64), 0, stream>>>(hfh, hfl, Wih0hh, Wih0hl, bih0, XcT, B);

  hipFuncSetAttribute((const void*)gru_main,
                      hipFuncAttributeMaxDynamicSharedMemorySize, LDS_BYTES);
  gru_main<<<dim3(B/RPB), dim3(NTHR), LDS_BYTES, stream>>>(
      istate, b1, b2, Wih0, bhh0, bih1, bhh1, Wout, bout,
      Whh0p, Wih1p, Whh1p, W1h, W1l, W2h, W2l, hfh, hfl, teW, XcT, out, B);
}

// Round 13
// 539.101 us; speedup vs baseline: 2.0607x; 2.0607x over previous
//
#include <hip/hip_runtime.h>

#define HDIM 256
#define KSTEPS 30
#define RPB 16            // rows per block (256 blocks -> all CUs)
#define NTHR 512          // 8 waves

typedef _Float16 f16x8 __attribute__((ext_vector_type(8)));
typedef float f32x4 __attribute__((ext_vector_type(4)));

__device__ __forceinline__ f32x4 mfma16(f16x8 a, f16x8 b, f32x4 c) {
  return __builtin_amdgcn_mfma_f32_16x16x32_f16(a, b, c, 0, 0, 0);
}

// fast transcendentals via v_exp_f32 / v_rcp_f32 (~2 ULP; threshold 0.037)
__device__ __forceinline__ float fsigm(float x) {
  return __builtin_amdgcn_rcpf(1.0f + __expf(-x));
}
__device__ __forceinline__ float ftanh(float x) {
  float t = __expf(2.0f * x);                 // inf for big x -> rcp=0 -> 1
  return 1.0f - 2.0f * __builtin_amdgcn_rcpf(t + 1.0f);
}
__device__ __forceinline__ float softplusf(float x) {
  return fmaxf(x, 0.0f) + log1pf(__expf(-fabsf(x)));
}

// swizzled byte offset for a [16][256] fp16 LDS tile (row stride 512B)
__device__ __forceinline__ int swz(int r, int c) {
  return r * 512 + ((c * 2) ^ ((r & 7) << 4));
}

__device__ __forceinline__ void wrsplit(char* hi, char* lo, int off, float v) {
  _Float16 h = (_Float16)v;
  *(_Float16*)(hi + off) = h;
  *(_Float16*)(lo + off) = (_Float16)(v - (float)h);
}
__device__ __forceinline__ float rdpair(const char* hi, const char* lo, int off) {
  return (float)*(const _Float16*)(hi + off) + (float)*(const _Float16*)(lo + off);
}

// async global->LDS, 16B per lane; dest = ldsbase + lane*16 (linear)
__device__ __forceinline__ void glds16(const _Float16* src, char* lds) {
  __builtin_amdgcn_global_load_lds(
      (const __attribute__((address_space(1))) unsigned int*)src,
      (__attribute__((address_space(3))) unsigned int*)lds, 16, 0, 0);
}

// stage one K=32 tile (6 frags x 1KB: [ct0:R,Z,N, ct1:R,Z,N]) into a slab buffer
// src is per-lane (includes lane*8)
__device__ __forceinline__ void stage6(const _Float16* src, char* dst) {
  glds16(src,        dst);
  glds16(src + 512,  dst + 1024);
  glds16(src + 1024, dst + 2048);
  glds16(src + 1536, dst + 3072);
  glds16(src + 2048, dst + 4096);
  glds16(src + 2560, dst + 5120);
}

#define WAITV(n) do { asm volatile("s_waitcnt vmcnt(" #n ")"); \
  __builtin_amdgcn_sched_barrier(0); } while (0)

// ---------------- prep: conversions + mfma16-order weight packing + teW ----------------
// Packed layout: p = ((w*8 + t)*6 + (ct*3 + g))*512 + lane*8 + j
//   lane = ks*16 + c (ks = K-subgroup 0-3, c = col 0-15)
//   src row = w*32 + ct*16 + c + g*256 ; src col = t*32 + ks*8 + j
// After glds16 (linear lane*16 dest), lane's mfma16 B-frag for (t, ct, g) is
// at slab + (ct*3+g)*1024 + lane*16 -> conflict-free 2-lanes/bank read.
__global__ __launch_bounds__(256) void prep_kernel(
    const float* __restrict__ W1, const float* __restrict__ W2,
    const float* __restrict__ Wih0, const float* __restrict__ Whh0,
    const float* __restrict__ Wih1, const float* __restrict__ Whh1,
    const float* __restrict__ hf,
    _Float16* __restrict__ Whh0p, _Float16* __restrict__ Wih1p,
    _Float16* __restrict__ Whh1p,
    _Float16* __restrict__ W1h, _Float16* __restrict__ W1l,
    _Float16* __restrict__ W2h, _Float16* __restrict__ W2l,
    _Float16* __restrict__ Wih0hh, _Float16* __restrict__ Wih0hl,
    _Float16* __restrict__ hfh, _Float16* __restrict__ hfl,
    float* __restrict__ teW, int B)
{
  int e = blockIdx.x * 256 + threadIdx.x;
  if (e < 3*196608) {
    int m = e / 196608, p = e % 196608;
    int j = p & 7;
    int lane = (p >> 3) & 63;
    int c = lane & 15, ks = lane >> 4;
    int fi = (p >> 9) % 6;
    int wt = p / 3072;
    int t = wt & 7, wv = wt >> 3;
    int ct = fi / 3, g = fi % 3;
    int row = wv*32 + ct*16 + c + g*256;
    int col = t*32 + ks*8 + j;
    const float* src = (m == 0) ? Whh0 : (m == 1) ? Wih1 : Whh1;
    _Float16* dst = (m == 0) ? Whh0p : (m == 1) ? Wih1p : Whh1p;
    dst[p] = (_Float16)src[row*256 + col];
    return;
  } e -= 3*196608;
  if (e < 65536)  { float x = W1[e]; _Float16 h = (_Float16)x; W1h[e] = h; W1l[e] = (_Float16)(x - (float)h); return; } e -= 65536;
  if (e < 131072) { float x = W2[e]; _Float16 h = (_Float16)x; W2h[e] = h; W2l[e] = (_Float16)(x - (float)h); return; } e -= 131072;
  if (e < 196608) { int n = e >> 8, c = e & 255; float x = Wih0[n*291 + 35 + c]; _Float16 h = (_Float16)x; Wih0hh[e] = h; Wih0hl[e] = (_Float16)(x - (float)h); return; } e -= 196608;
  if (e < B*HDIM) { float x = hf[e]; _Float16 h = (_Float16)x; hfh[e] = h; hfl[e] = (_Float16)(x - (float)h); return; } e -= B*HDIM;
  if (e < KSTEPS*768) {
    int k = e / 768, n = e % 768;
    float pos = (float)k;
    const float fac = -9.210340371976184f / 31.0f;   // -ln(10000)/(TD-1)
    float acc = 0.0f;
    #pragma unroll
    for (int j = 0; j < 31; ++j) {
      int i = j >> 1;
      float ang = pos * expf((float)(2*i) * fac);
      float t = (j & 1) ? cosf(ang) : sinf(ang);
      acc += t * Wih0[n*291 + 3 + j];
    }
    acc += (pos / 30.0f) * Wih0[n*291 + 3 + 31];
    teW[e] = acc;
  }
}

// ------- XcT[n*B + r] = (hf @ Wih0[:,35:291].T)[r,n] + bih0[n]  (transposed, f32) -------
__global__ __launch_bounds__(64) void xc_kernel(
    const _Float16* __restrict__ hfh, const _Float16* __restrict__ hfl,
    const _Float16* __restrict__ Wh, const _Float16* __restrict__ Wl,
    const float* __restrict__ bih0, float* __restrict__ XcT, int B)
{
  int l = threadIdx.x, l15 = l & 15, l4 = l >> 4;
  int bm = blockIdx.x;
  int bn = blockIdx.y;
  f32x4 acc[4];
  #pragma unroll
  for (int i = 0; i < 4; ++i) acc[i] = (f32x4){0,0,0,0};
  const _Float16* ah = hfh + (size_t)(bm*16 + l15)*256 + l4*8;
  const _Float16* al = hfl + (size_t)(bm*16 + l15)*256 + l4*8;
  #pragma unroll
  for (int kk = 0; kk < 8; ++kk) {
    f16x8 aH = *(const f16x8*)(ah + kk*32);
    f16x8 aL = *(const f16x8*)(al + kk*32);
    #pragma unroll
    for (int i = 0; i < 4; ++i) {
      size_t boff = (size_t)(bn*64 + i*16 + l15)*256 + l4*8 + kk*32;
      f16x8 bH = *(const f16x8*)(Wh + boff);
      f16x8 bL = *(const f16x8*)(Wl + boff);
      acc[i] = mfma16(aH, bH, acc[i]);
      acc[i] = mfma16(aL, bH, acc[i]);
      acc[i] = mfma16(aH, bL, acc[i]);
    }
  }
  #pragma unroll
  for (int i = 0; i < 4; ++i) {
    int n = bn*64 + i*16 + l15;
    float bb = bih0[n];
    #pragma unroll
    for (int j = 0; j < 4; ++j) {
      int r = bm*16 + l4*4 + j;
      XcT[(size_t)n*B + r] = acc[i][j] + bb;
    }
  }
}

// ---------------- main persistent GRU kernel ----------------
// LDS map (bytes); h tiles [16][256] fp16 swizzled, 8KB each
#define OFF_H0H   0
#define OFF_H0L   8192
#define OFF_H1H   16384
#define OFF_H1L   24576
#define OFF_SLAB  32768    // 2 bufs x 48KB (8 waves x 6KB); also hmid temp in h_init
#define OFF_WS3   131072   // 768*3 f32
#define OFF_BHH0  140288
#define OFF_BI1   143360
#define OFF_BH1   146432
#define OFF_WOUT  149504
#define OFF_SPH   152576   // 16*8 f32
#define OFF_BOUT  153088
#define LDS_BYTES 153104   // <= 163840

__global__ __launch_bounds__(NTHR) void gru_main(
    const float* __restrict__ istate,
    const float* __restrict__ b1g, const float* __restrict__ b2g,
    const float* __restrict__ Wih0, const float* __restrict__ bhh0g,
    const float* __restrict__ bih1g, const float* __restrict__ bhh1g,
    const float* __restrict__ Woutg, const float* __restrict__ boutg,
    const _Float16* __restrict__ Whh0p, const _Float16* __restrict__ Wih1p,
    const _Float16* __restrict__ Whh1p,
    const _Float16* __restrict__ W1h, const _Float16* __restrict__ W1l,
    const _Float16* __restrict__ W2h, const _Float16* __restrict__ W2l,
    const _Float16* __restrict__ hfh, const _Float16* __restrict__ hfl,
    const float* __restrict__ teW, const float* __restrict__ XcT,
    float* __restrict__ out, int B)
{
  extern __shared__ char smem[];
  char* h0H = smem + OFF_H0H;  char* h0L = smem + OFF_H0L;
  char* h1H = smem + OFF_H1H;  char* h1L = smem + OFF_H1L;
  float* Ws3   = (float*)(smem + OFF_WS3);
  float* bhh0L = (float*)(smem + OFF_BHH0);
  float* bi1L  = (float*)(smem + OFF_BI1);
  float* bh1L  = (float*)(smem + OFF_BH1);
  float* WoutL = (float*)(smem + OFF_WOUT);
  float* sph   = (float*)(smem + OFF_SPH);
  float* boutL = (float*)(smem + OFF_BOUT);

  const int tid = threadIdx.x;
  const int w = tid >> 6;
  const int lane = tid & 63;
  const int l15 = lane & 15;
  const int l4 = lane >> 4;
  const int row0 = blockIdx.x * RPB;

  // wave-uniform slab bases (per-wave private 6KB region in each of 2 buffers)
  const int wsb = __builtin_amdgcn_readfirstlane(OFF_SLAB + w * 6144);
  char* sl0 = smem + wsb;
  char* sl1 = sl0 + 49152;

  // per-lane packed-weight bases (tile stride 3072 elems)
  const _Float16* wpB  = Whh0p + (size_t)w*24576 + lane*8;
  const _Float16* wpH1 = Whh1p + (size_t)w*24576 + lane*8;
  const _Float16* wpI1 = Wih1p + (size_t)w*24576 + lane*8;

  // ---- constants to LDS
  for (int i = tid; i < 2304; i += NTHR) Ws3[i] = Wih0[(i/3)*291 + (i%3)];
  for (int i = tid; i < 768; i += NTHR) {
    bhh0L[i] = bhh0g[i]; bi1L[i] = bih1g[i]; bh1L[i] = bhh1g[i]; WoutL[i] = Woutg[i];
  }
  if (tid < 3) boutL[tid] = boutg[tid];
  if (tid < RPB) {
    const float* is = istate + (size_t)(row0 + tid) * 3;
    float s0 = is[0], s1 = is[1], s2 = is[2];
    float* sp = sph + tid*8;
    sp[0] = s0; sp[1] = s1; sp[2] = s2;
    sp[3] = s0; sp[4] = s0; sp[5] = s0;
  }

  // ---- h_init GEMM1: relu(hf @ W1.T + b1), 16 rows -> hmid (hi/lo) in slab region
  {
    char* mH = smem + OFF_SLAB;
    char* mL = smem + OFF_SLAB + 8192;
    #pragma unroll
    for (int i = 0; i < 2; ++i) {
      int nt = w*2 + i;
      f32x4 acc0 = {0,0,0,0};
      const _Float16* brh = W1h + (nt*16 + l15)*256 + l4*8;
      const _Float16* brl = W1l + (nt*16 + l15)*256 + l4*8;
      const _Float16* a0h = hfh + (size_t)(row0 + l15)*256 + l4*8;
      const _Float16* a0l = hfl + (size_t)(row0 + l15)*256 + l4*8;
      #pragma unroll
      for (int kk = 0; kk < 8; ++kk) {
        f16x8 bH = *(const f16x8*)(brh + kk*32);
        f16x8 bL = *(const f16x8*)(brl + kk*32);
        f16x8 aH0 = *(const f16x8*)(a0h + kk*32);
        f16x8 aL0 = *(const f16x8*)(a0l + kk*32);
        acc0 = mfma16(aH0, bH, acc0); acc0 = mfma16(aL0, bH, acc0); acc0 = mfma16(aH0, bL, acc0);
      }
      int n = nt*16 + l15;
      float bb = b1g[n];
      #pragma unroll
      for (int j = 0; j < 4; ++j) {
        int r = l4*4 + j;
        float v = fmaxf(acc0[j] + bb, 0.0f);
        wrsplit(mH, mL, swz(r, n), v);
      }
    }
  }
  __syncthreads();

  // ---- h_init GEMM2: tanh(hmid @ W2.T + b2) -> h0 / h1 (hi/lo), 16 rows
  {
    const char* mH = smem + OFF_SLAB;
    const char* mL = smem + OFF_SLAB + 8192;
    #pragma unroll
    for (int i = 0; i < 4; ++i) {
      int nt = w*4 + i;
      f32x4 acc0 = {0,0,0,0};
      const _Float16* brh = W2h + (nt*16 + l15)*256 + l4*8;
      const _Float16* brl = W2l + (nt*16 + l15)*256 + l4*8;
      #pragma unroll
      for (int kk = 0; kk < 8; ++kk) {
        int kc = kk*32 + l4*8;
        f16x8 bH = *(const f16x8*)(brh + kk*32);
        f16x8 bL = *(const f16x8*)(brl + kk*32);
        f16x8 aH0 = *(const f16x8*)(mH + swz(l15, kc));
        f16x8 aL0 = *(const f16x8*)(mL + swz(l15, kc));
        acc0 = mfma16(aH0, bH, acc0); acc0 = mfma16(aL0, bH, acc0); acc0 = mfma16(aH0, bL, acc0);
      }
      int n = nt*16 + l15;
      float bb = b2g[n];
      #pragma unroll
      for (int j = 0; j < 4; ++j) {
        int r = l4*4 + j;
        float v = ftanh(acc0[j] + bb);
        if (n < 256) wrsplit(h0H, h0L, swz(r, n), v);
        else         wrsplit(h1H, h1L, swz(r, n - 256), v);
      }
    }
  }
  __syncthreads();

  const size_t outP = (size_t)B * KSTEPS;
  const int boff = lane * 16;          // packed slab B-frag offset: conflict-free
  const int n0 = w*32 + l15;           // ct=0 output col (per gate)
  const int n1 = n0 + 16;              // ct=1 output col

  // prologue: stage step-0 B tile 0 into sl0
  stage6(wpB, sl0);

  for (int k = 0; k < KSTEPS; ++k) {
    const float* teWk = teW + k*768;

    // ================= Phase B: gh0 = h0 @ Whh0.T (rolled, 2-buf, dist-1) ===
    f32x4 cR0 = {0,0,0,0}, cZ0 = {0,0,0,0}, cN0 = {0,0,0,0};
    f32x4 cR1 = {0,0,0,0}, cZ1 = {0,0,0,0}, cN1 = {0,0,0,0};
    #define GBODY(buf, t, AH, AL, r0, z0, nn0, r1, z1, nn1) do {      \
      f16x8 b0 = *(const f16x8*)((buf) + boff);                       \
      f16x8 b1 = *(const f16x8*)((buf) + 1024 + boff);                \
      f16x8 b2 = *(const f16x8*)((buf) + 2048 + boff);                \
      f16x8 b3 = *(const f16x8*)((buf) + 3072 + boff);                \
      f16x8 b4 = *(const f16x8*)((buf) + 4096 + boff);                \
      f16x8 b5 = *(const f16x8*)((buf) + 5120 + boff);                \
      int aoff = swz(l15, (t)*32 + l4*8);                             \
      f16x8 aH = *(const f16x8*)((AH) + aoff);                        \
      f16x8 aL = *(const f16x8*)((AL) + aoff);                        \
      r0  = mfma16(aH, b0, r0);  r0  = mfma16(aL, b0, r0);            \
      z0  = mfma16(aH, b1, z0);  z0  = mfma16(aL, b1, z0);            \
      nn0 = mfma16(aH, b2, nn0); nn0 = mfma16(aL, b2, nn0);           \
      r1  = mfma16(aH, b3, r1);  r1  = mfma16(aL, b3, r1);            \
      z1  = mfma16(aH, b4, z1);  z1  = mfma16(aL, b4, z1);            \
      nn1 = mfma16(aH, b5, nn1); nn1 = mfma16(aL, b5, nn1);           \
    } while (0)
    {
      char *cur = sl0, *nxt = sl1;
      for (int t = 0; t < 8; ++t) {              // ROLLED: no unroll pragma
        const _Float16* nsrc = (t < 7) ? (wpB + (t+1)*3072) : wpH1;
        stage6(nsrc, nxt);
        WAITV(6);
        GBODY(cur, t, h0H, h0L, cR0, cZ0, cN0, cR1, cZ1, cN1);
        char* tmp = cur; cur = nxt; nxt = tmp;
      }
    }
    __syncthreads();   // all waves done reading h0_old

    // ---- GRU-0 epilogue, in-place h0 update (XcT loaded here, post-K-loop)
    #define EPI0(n, accR, accZ, accN) do {                                      \
      size_t base = (size_t)row0 + l4*4;                                        \
      f32x4 xcR = *(const f32x4*)(XcT + (size_t)(n)*B + base);                  \
      f32x4 xcZ = *(const f32x4*)(XcT + (size_t)(256 + (n))*B + base);          \
      f32x4 xcN = *(const f32x4*)(XcT + (size_t)(512 + (n))*B + base);          \
      float teR = teWk[n], teZ = teWk[256 + (n)], teN = teWk[512 + (n)];        \
      float wR0 = Ws3[(n)*3+0],       wR1 = Ws3[(n)*3+1],       wR2 = Ws3[(n)*3+2];          \
      float wZ0 = Ws3[((n)+256)*3+0], wZ1 = Ws3[((n)+256)*3+1], wZ2 = Ws3[((n)+256)*3+2];    \
      float wN0 = Ws3[((n)+512)*3+0], wN1 = Ws3[((n)+512)*3+1], wN2 = Ws3[((n)+512)*3+2];    \
      float bhR = bhh0L[n], bhZ = bhh0L[256 + (n)], bhN = bhh0L[512 + (n)];     \
      _Pragma("unroll")                                                         \
      for (int j = 0; j < 4; ++j) {                                             \
        int r = l4*4 + j;                                                       \
        const float* sp = sph + r*8;                                            \
        float s0 = sp[0], s1 = sp[1], s2 = sp[2];                               \
        float giR = xcR[j] + teR + s0*wR0 + s1*wR1 + s2*wR2;                    \
        float giZ = xcZ[j] + teZ + s0*wZ0 + s1*wZ1 + s2*wZ2;                    \
        float giN = xcN[j] + teN + s0*wN0 + s1*wN1 + s2*wN2;                    \
        float rg = fsigm(giR + accR[j] + bhR);                                  \
        float zg = fsigm(giZ + accZ[j] + bhZ);                                  \
        float ng = ftanh(giN + rg * (accN[j] + bhN));                           \
        float hold = rdpair(h0H, h0L, swz(r, n));                               \
        float hnew = (1.0f - zg) * ng + zg * hold;                              \
        wrsplit(h0H, h0L, swz(r, n), hnew);                                     \
      }                                                                         \
    } while (0)
    EPI0(n0, cR0, cZ0, cN0);
    EPI0(n1, cR1, cZ1, cN1);
    #undef EPI0
    __syncthreads();   // h0_new visible to all

    // ===== Phase AC: K=512 concat GEMM [h1_old; h0_new] @ [Whh1; Wih1].T ====
    f32x4 aR0 = {0,0,0,0}, aZ0 = {0,0,0,0}, hN0 = {0,0,0,0}, iN0 = {0,0,0,0};
    f32x4 aR1 = {0,0,0,0}, aZ1 = {0,0,0,0}, hN1 = {0,0,0,0}, iN1 = {0,0,0,0};
    {
      char *cur = sl0, *nxt = sl1;
      for (int t = 0; t < 8; ++t) {              // sub0: h1_old x Whh1 (rolled)
        const _Float16* nsrc = (t < 7) ? (wpH1 + (t+1)*3072) : wpI1;
        stage6(nsrc, nxt);
        WAITV(6);
        GBODY(cur, t, h1H, h1L, aR0, aZ0, hN0, aR1, aZ1, hN1);
        char* tmp = cur; cur = nxt; nxt = tmp;
      }
      for (int t = 0; t < 8; ++t) {              // sub1: h0_new x Wih1 (rolled)
        const _Float16* nsrc = (t < 7) ? (wpI1 + (t+1)*3072) : wpB;
        stage6(nsrc, nxt);                       // t=7 prefetches next step's B tile 0
        WAITV(6);
        GBODY(cur, t, h0H, h0L, aR0, aZ0, iN0, aR1, aZ1, iN1);
        char* tmp = cur; cur = nxt; nxt = tmp;
      }
    }
    #undef GBODY
    __syncthreads();   // all waves done reading h1_old

    // ---- GRU-1 epilogue, in-place h1 update
    #define EPI1(n, accR, accZ, accHN, accIN) do {                              \
      float biR = bi1L[n], biZ = bi1L[256+(n)], biN = bi1L[512+(n)];            \
      float bhRb = bh1L[n], bhZb = bh1L[256+(n)], bhNb = bh1L[512+(n)];         \
      _Pragma("unroll")                                                         \
      for (int j = 0; j < 4; ++j) {                                             \
        int r = l4*4 + j;                                                       \
        float rg = fsigm(accR[j] + biR + bhRb);                                 \
        float zg = fsigm(accZ[j] + biZ + bhZb);                                 \
        float ng = ftanh(accIN[j] + biN + rg * (accHN[j] + bhNb));              \
        float hold = rdpair(h1H, h1L, swz(r, n));                               \
        float hnew = (1.0f - zg) * ng + zg * hold;                              \
        wrsplit(h1H, h1L, swz(r, n), hnew);                                     \
      }                                                                         \
    } while (0)
    EPI1(n0, aR0, aZ0, hN0, iN0);
    EPI1(n1, aR1, aZ1, hN1, iN1);
    #undef EPI1
    __syncthreads();   // h1_new visible

    // ---- Phase D: qr = h1n @ Wout.T + bout (16 rows x 32 lanes)
    {
      int r = tid >> 5, li = tid & 31;
      float q0 = 0.0f, q1 = 0.0f, q2 = 0.0f;
      #pragma unroll
      for (int i = 0; i < 8; ++i) {
        int h = li + i*32;
        float v = rdpair(h1H, h1L, swz(r, h));
        q0 += v * WoutL[h];
        q1 += v * WoutL[256 + h];
        q2 += v * WoutL[512 + h];
      }
      #pragma unroll
      for (int m = 1; m < 32; m <<= 1) {
        q0 += __shfl_xor(q0, m);
        q1 += __shfl_xor(q1, m);
        q2 += __shfl_xor(q2, m);
      }
      if (li == 0) {
        float qlo = q0 + boutL[0];
        float qm  = qlo + softplusf(q1 + boutL[1] - qlo);
        float qhi = qm  + softplusf(q2 + boutL[2] - qm);
        size_t b = row0 + r;
        out[b*KSTEPS + k]            = qlo;
        out[outP + b*KSTEPS + k]     = qm;
        out[2*outP + b*KSTEPS + k]   = qhi;
        float* sp = sph + r*8;
        float p1 = sp[4], p2 = sp[5];
        sp[0] = qm;
        sp[1] = (qm - p1) * 5.0f;
        sp[2] = (qm - 2.0f*p2 + p1) * 100.0f;
        sp[3] = p1; sp[4] = p2; sp[5] = qm;
      }
    }
    // no barrier: next B K-loop reads only h0 + weight slabs (not h1/sph);
    // the first sph/h1 consumers are >=1 barrier away
  }
}

extern "C" void kernel_launch(void* const* d_in, const int* in_sizes, int n_in,
                              void* d_out, int out_size, void* d_ws, size_t ws_size,
                              hipStream_t stream) {
  const float* hf     = (const float*)d_in[0];
  const float* istate = (const float*)d_in[1];
  const float* W1     = (const float*)d_in[2];
  const float* b1     = (const float*)d_in[3];
  const float* W2     = (const float*)d_in[4];
  const float* b2     = (const float*)d_in[5];
  const float* Wih0   = (const float*)d_in[6];
  const float* Whh0   = (const float*)d_in[7];
  const float* bih0   = (const float*)d_in[8];
  const float* bhh0   = (const float*)d_in[9];
  const float* Wih1   = (const float*)d_in[10];
  const float* Whh1   = (const float*)d_in[11];
  const float* bih1   = (const float*)d_in[12];
  const float* bhh1   = (const float*)d_in[13];
  const float* Wout   = (const float*)d_in[14];
  const float* bout   = (const float*)d_in[15];
  float* out = (float*)d_out;
  const int B = in_sizes[0] / HDIM;   // 4096

  char* ws = (char*)d_ws;
  size_t o = 0;
  _Float16* Whh0p  = (_Float16*)(ws + o); o += 393216;
  _Float16* Wih1p  = (_Float16*)(ws + o); o += 393216;
  _Float16* Whh1p  = (_Float16*)(ws + o); o += 393216;
  _Float16* W1h    = (_Float16*)(ws + o); o += 131072;
  _Float16* W1l    = (_Float16*)(ws + o); o += 131072;
  _Float16* W2h    = (_Float16*)(ws + o); o += 262144;
  _Float16* W2l    = (_Float16*)(ws + o); o += 262144;
  _Float16* Wih0hh = (_Float16*)(ws + o); o += 393216;
  _Float16* Wih0hl = (_Float16*)(ws + o); o += 393216;
  _Float16* hfh    = (_Float16*)(ws + o); o += (size_t)B * HDIM * 2;
  _Float16* hfl    = (_Float16*)(ws + o); o += (size_t)B * HDIM * 2;
  float*    teW    = (float*)(ws + o);    o += (size_t)KSTEPS * 768 * 4;
  float*    XcT    = (float*)(ws + o);    o += (size_t)B * 768 * 4;
  if (ws_size < o) return;

  const int prep_total = 196608*3 + 65536 + 131072 + 196608 + B*HDIM + KSTEPS*768;
  prep_kernel<<<dim3((prep_total + 255) / 256), dim3(256), 0, stream>>>(
      W1, W2, Wih0, Whh0, Wih1, Whh1, hf,
      Whh0p, Wih1p, Whh1p, W1h, W1l, W2h, W2l, Wih0hh, Wih0hl, hfh, hfl, teW, B);

  xc_kernel<<<dim3(B/16, 12), dim3(64), 0, stream>>>(hfh, hfl, Wih0hh, Wih0hl, bih0, XcT, B);

  hipFuncSetAttribute((const void*)gru_main,
                      hipFuncAttributeMaxDynamicSharedMemorySize, LDS_BYTES);
  gru_main<<<dim3(B/RPB), dim3(NTHR), LDS_BYTES, stream>>>(
      istate, b1, b2, Wih0, bhh0, bih1, bhh1, Wout, bout,
      Whh0p, Wih1p, Whh1p, W1h, W1l, W2h, W2l, hfh, hfl, teW, XcT, out, B);
}